// Round 2
// baseline (119.587 us; speedup 1.0000x reference)
//
#include <hip/hip_runtime.h>

#define NPATCH 16384
#define NDB    16384
#define WS9    9
#define KP     16               // K padded 9 -> 16 for 32x32x16 MFMA
#define JCH    32               // db chunks (grid.y)
#define CHUNK  (NDB / JCH)      // 512 rows per chunk
#define TILES  (CHUNK / 32)     // 16 j-tiles per chunk
// Split-bf16 cosmax error vs numpy fp32 path <= ~6e-6. Band +-2e-5 keeps 3x
// margin; band population ~= 80 patches over 64 groups -> inline recheck is
// ~1-2 entries per last-arriver block.
#define BAND_LO 0.89998f
#define BAND_HI 0.90002f
#define PREP_BLOCKS 144         // 36864 threads: 32768 prep rows + 36864 float4 copy

typedef short bf16x8 __attribute__((ext_vector_type(8)));
typedef float f32x16 __attribute__((ext_vector_type(16)));

#define MAX3(a,b,c) fmaxf(fmaxf((a),(b)),(c))

// numpy-order norm of 9 elements: sqrt(pairwise-8 + remainder), no contraction.
__device__ __forceinline__ float np_norm9(const float* v) {
#pragma clang fp contract(off)
    float q0 = v[0] * v[0], q1 = v[1] * v[1], q2 = v[2] * v[2], q3 = v[3] * v[3];
    float q4 = v[4] * v[4], q5 = v[5] * v[5], q6 = v[6] * v[6], q7 = v[7] * v[7];
    float q8 = v[8] * v[8];
    float s = ((q0 + q1) + (q2 + q3)) + ((q4 + q5) + (q6 + q7));
    s = s + q8;
    return sqrtf(s);
}

// fp32 -> bf16 RTNE (no NaN inputs here), and back
__device__ __forceinline__ unsigned short f2bf(float x) {
    unsigned u = __float_as_uint(x);
    return (unsigned short)((u + 0x7fffu + ((u >> 16) & 1u)) >> 16);
}
__device__ __forceinline__ float bf2f(unsigned short h) {
    return __uint_as_float(((unsigned)h) << 16);
}

// Order-preserving float<->int key (no NaNs here). max over keys == fmax.
__device__ __forceinline__ int enc_key(float f) {
    int k = __float_as_int(f);
    return (k >= 0) ? k : (k ^ 0x7FFFFFFF);
}
__device__ __forceinline__ float dec_key(int k) {
    return __int_as_float((k >= 0) ? k : (k ^ 0x7FFFFFFF));
}

// load row of 9, normalize, split to bf16 hi/lo, K-pad to 16, pack 2x int4 per
// array. Bit-identical to the proven staging (absmax=0).
__device__ __forceinline__ void stage_row(const float* __restrict__ src,
                                          unsigned short* dh, unsigned short* dl) {
    float v[WS9];
#pragma unroll
    for (int k = 0; k < WS9; k++) v[k] = src[k];
    float inv = 1.0f / np_norm9(v);
    unsigned short h[KP], l[KP];
#pragma unroll
    for (int k = 0; k < KP; k++) {
        float x = (k < WS9) ? v[k] * inv : 0.0f;
        h[k] = f2bf(x);
        l[k] = f2bf(x - bf2f(h[k]));
    }
    int hw[8], lw[8];
#pragma unroll
    for (int k = 0; k < 8; k++) {
        hw[k] = (int)h[2 * k] | ((int)h[2 * k + 1] << 16);
        lw[k] = (int)l[2 * k] | ((int)l[2 * k + 1] << 16);
    }
    ((int4*)dh)[0] = make_int4(hw[0], hw[1], hw[2], hw[3]);
    ((int4*)dh)[1] = make_int4(hw[4], hw[5], hw[6], hw[7]);
    ((int4*)dl)[0] = make_int4(lw[0], lw[1], lw[2], lw[3]);
    ((int4*)dl)[1] = make_int4(lw[4], lw[5], lw[6], lw[7]);
}

// K0: one-shot prep. Normalize+split every row once, db->out copy, and init
// cosk (key(-inf) floor = INT_MIN) + per-group done counters. All plain
// stores; kernel boundary on the stream makes them visible to k_main.
__global__ __launch_bounds__(256) void k_prep(const float* __restrict__ patches,
                                              const float* __restrict__ db,
                                              unsigned short* __restrict__ pnh,
                                              unsigned short* __restrict__ pnl,
                                              unsigned short* __restrict__ dnh,
                                              unsigned short* __restrict__ dnl,
                                              float* __restrict__ out,
                                              int* __restrict__ cosk,
                                              int* __restrict__ done) {
    int t = blockIdx.x * 256 + threadIdx.x;       // [0, 36864)
    // db -> out rows [0, NDB): 147456 floats = 36864 float4
    ((float4*)out)[t] = ((const float4*)db)[t];
    if (t < NPATCH) {
        cosk[t] = (int)0x80000000;                // below every encoded float
        stage_row(patches + (size_t)t * WS9, &pnh[(size_t)t * KP], &pnl[(size_t)t * KP]);
    } else if (t < 2 * NPATCH) {
        int r = t - NPATCH;
        stage_row(db + (size_t)r * WS9, &dnh[(size_t)r * KP], &dnl[(size_t)r * KP]);
    }
    if (t < NPATCH / 256) done[t] = 0;            // 64 group counters
}

// K1: fused phase1 + last-arriver classify + inline exact recheck.
// Block = 256 patches (x) x 512-row db chunk (y). Chunk cos-max folded into
// cosk[i] via order-preserving atomicMax; the 32nd arriver per patch group
// classifies its 256 patches (definite rows written, band entries rechecked
// against raw db with the exact numpy-mirror path).
__global__ __launch_bounds__(256) void k_main(const unsigned short* __restrict__ pnh,
                                              const unsigned short* __restrict__ pnl,
                                              const unsigned short* __restrict__ dnh,
                                              const unsigned short* __restrict__ dnl,
                                              const float* __restrict__ patches,
                                              const float* __restrict__ db,
                                              float* __restrict__ out,
                                              int* __restrict__ cosk,
                                              int* __restrict__ done) {
    __shared__ __align__(16) unsigned short s_dh[CHUNK * KP];   // 16 KB
    __shared__ __align__(16) unsigned short s_dl[CHUNK * KP];   // 16 KB
    __shared__ int s_old;
    __shared__ int s_bn;
    __shared__ int s_blist[256];
    __shared__ float sp[WS9];
    __shared__ float snp;
    __shared__ int shit;

    int jbase = blockIdx.y * CHUNK;
    int ibase = blockIdx.x * 256;

    int lane = threadIdx.x & 63;
    int wave = threadIdx.x >> 6;
    int col = lane & 31;
    int half = lane >> 5;
    int i0 = ibase + wave * 64;

    // patch b-frags straight from prepped global (L2/L3-resident, high reuse)
    const bf16x8* Ph = (const bf16x8*)pnh;        // 2 frags per 16-elem row
    const bf16x8* Pl = (const bf16x8*)pnl;
    bf16x8 b_hi0 = Ph[(size_t)(i0 + col) * 2 + half];
    bf16x8 b_lo0 = Pl[(size_t)(i0 + col) * 2 + half];
    bf16x8 b_hi1 = Ph[(size_t)(i0 + 32 + col) * 2 + half];
    bf16x8 b_lo1 = Pl[(size_t)(i0 + 32 + col) * 2 + half];

    {   // stage db chunk: 512 rows x 32B per array = 16KB each
        const int4* gh = (const int4*)(dnh + (size_t)jbase * KP);
        const int4* gl = (const int4*)(dnl + (size_t)jbase * KP);
        int4* sh = (int4*)s_dh;
        int4* sl = (int4*)s_dl;
#pragma unroll
        for (int u = 0; u < 4; u++) {
            int e = u * 256 + threadIdx.x;        // 1024 int4 per array
            sh[e] = gh[e];
            sl[e] = gl[e];
        }
    }
    __syncthreads();

    const bf16x8* Ah = (const bf16x8*)s_dh;
    const bf16x8* Al = (const bf16x8*)s_dl;

    f32x16 zc = {0.f,0.f,0.f,0.f,0.f,0.f,0.f,0.f,0.f,0.f,0.f,0.f,0.f,0.f,0.f,0.f};
    float rm0 = -3.0e38f, rm1 = -3.0e38f;

#pragma unroll 2
    for (int t = 0; t < TILES; ++t) {
        bf16x8 a_h = Ah[(t * 32 + col) * 2 + half];
        bf16x8 a_l = Al[(t * 32 + col) * 2 + half];
        f32x16 acc0 = __builtin_amdgcn_mfma_f32_32x32x16_bf16(a_h, b_hi0, zc, 0, 0, 0);
        acc0 = __builtin_amdgcn_mfma_f32_32x32x16_bf16(a_h, b_lo0, acc0, 0, 0, 0);
        acc0 = __builtin_amdgcn_mfma_f32_32x32x16_bf16(a_l, b_hi0, acc0, 0, 0, 0);
        f32x16 acc1 = __builtin_amdgcn_mfma_f32_32x32x16_bf16(a_h, b_hi1, zc, 0, 0, 0);
        acc1 = __builtin_amdgcn_mfma_f32_32x32x16_bf16(a_h, b_lo1, acc1, 0, 0, 0);
        acc1 = __builtin_amdgcn_mfma_f32_32x32x16_bf16(a_l, b_hi1, acc1, 0, 0, 0);
        // max3-fusable tree, depth 3
        {
            float u0 = MAX3(acc0[0],  acc0[1],  acc0[2]);
            float u1 = MAX3(acc0[3],  acc0[4],  acc0[5]);
            float u2 = MAX3(acc0[6],  acc0[7],  acc0[8]);
            float u3 = MAX3(acc0[9],  acc0[10], acc0[11]);
            float u4 = MAX3(acc0[12], acc0[13], acc0[14]);
            float u5 = MAX3(u0, u1, acc0[15]);
            float u6 = MAX3(u2, u3, u4);
            rm0 = MAX3(u5, u6, rm0);
        }
        {
            float u0 = MAX3(acc1[0],  acc1[1],  acc1[2]);
            float u1 = MAX3(acc1[3],  acc1[4],  acc1[5]);
            float u2 = MAX3(acc1[6],  acc1[7],  acc1[8]);
            float u3 = MAX3(acc1[9],  acc1[10], acc1[11]);
            float u4 = MAX3(acc1[12], acc1[13], acc1[14]);
            float u5 = MAX3(u0, u1, acc1[15]);
            float u6 = MAX3(u2, u3, u4);
            rm1 = MAX3(u5, u6, rm1);
        }
    }
    rm0 = fmaxf(rm0, __shfl_xor(rm0, 32, 64));
    rm1 = fmaxf(rm1, __shfl_xor(rm1, 32, 64));
    int ti = half ? (i0 + 32 + col) : (i0 + col);
    atomicMax(&cosk[ti], enc_key(half ? rm1 : rm0));

    // --- last-arriver classification for this patch group ---
    __syncthreads();   // barrier drains vmcnt: all block atomics complete
    if (threadIdx.x == 0) {
        s_old = __hip_atomic_fetch_add(&done[blockIdx.x], 1,
                                       __ATOMIC_ACQ_REL, __HIP_MEMORY_SCOPE_AGENT);
        s_bn = 0;
    }
    __syncthreads();
    if (s_old != JCH - 1) return;   // not the last chunk for this group

    int i = ibase + threadIdx.x;
    int key = __hip_atomic_load(&cosk[i], __ATOMIC_ACQUIRE, __HIP_MEMORY_SCOPE_AGENT);
    float cosmax = dec_key(key);
    if (cosmax >= BAND_LO && cosmax < BAND_HI) {
        int idx = atomicAdd(&s_bn, 1);
        s_blist[idx] = i;
    } else {
        int hit = (cosmax >= BAND_HI) ? 1 : 0;
#pragma unroll
        for (int k = 0; k < WS9; k++)
            out[(size_t)(NDB + i) * WS9 + k] = hit ? 0.0f : patches[(size_t)i * WS9 + k];
    }
    __syncthreads();
    int nb = s_bn;

    // exact numpy-mirror recheck for band entries (typically 0-2 per group)
    for (int e = 0; e < nb; e++) {
        int bi = s_blist[e];
        if (threadIdx.x == 0) {
            float p[WS9];
            for (int k = 0; k < WS9; k++) { p[k] = patches[(size_t)bi * WS9 + k]; sp[k] = p[k]; }
            snp = np_norm9(p);
            shit = 0;
        }
        __syncthreads();
        float p[WS9];
#pragma unroll
        for (int k = 0; k < WS9; k++) p[k] = sp[k];
        float npn = snp;
        int hit = 0;
        for (int j = (int)threadIdx.x; j < NDB; j += 256) {
            float d[WS9];
#pragma unroll
            for (int k = 0; k < WS9; k++) d[k] = db[(size_t)j * WS9 + k];
            float dot = 0.0f;
#pragma unroll
            for (int k = 0; k < WS9; k++) dot = fmaf(p[k], d[k], dot);
            float nd = np_norm9(d);
            float cs = dot / (npn * nd);          // IEEE fp32 divide
            if (!((double)cs < 0.9)) hit = 1;     // numpy promotes to f64
        }
        if (hit) atomicOr(&shit, 1);
        __syncthreads();
        int m = shit;
        if (threadIdx.x < WS9)
            out[(size_t)(NDB + bi) * WS9 + threadIdx.x] = m ? 0.0f : sp[threadIdx.x];
        __syncthreads();
    }
}

extern "C" void kernel_launch(void* const* d_in, const int* in_sizes, int n_in,
                              void* d_out, int out_size, void* d_ws, size_t ws_size,
                              hipStream_t stream) {
    const float* patches = (const float*)d_in[0];  // [16384][9]
    const float* db      = (const float*)d_in[1];  // [16384][9]
    float* out = (float*)d_out;                    // [32768][9]

    // ws layout: cosk (64 KB) | done (pad 256 B) | pnh | pnl | dnh | dnl (512 KB each)
    char* wsb = (char*)d_ws;
    size_t o_cosk = 0;
    size_t o_done = (size_t)NPATCH * 4;            // 64 KB
    size_t o_pnh  = o_done + 256;
    size_t o_pnl  = o_pnh + (size_t)NPATCH * KP * 2;
    size_t o_dnh  = o_pnl + (size_t)NPATCH * KP * 2;
    size_t o_dnl  = o_dnh + (size_t)NDB * KP * 2;

    int* cosk           = (int*)(wsb + o_cosk);
    int* done           = (int*)(wsb + o_done);
    unsigned short* pnh = (unsigned short*)(wsb + o_pnh);
    unsigned short* pnl = (unsigned short*)(wsb + o_pnl);
    unsigned short* dnh = (unsigned short*)(wsb + o_dnh);
    unsigned short* dnl = (unsigned short*)(wsb + o_dnl);

    k_prep<<<dim3(PREP_BLOCKS), dim3(256), 0, stream>>>(patches, db, pnh, pnl,
                                                        dnh, dnl, out, cosk, done);
    k_main<<<dim3(NPATCH / 256, JCH), dim3(256), 0, stream>>>(pnh, pnl, dnh, dnl,
                                                              patches, db, out,
                                                              cosk, done);
}

// Round 3
// 95.862 us; speedup vs baseline: 1.2475x; 1.2475x over previous
//
#include <hip/hip_runtime.h>

#define NPATCH 16384
#define NDB    16384
#define WS9    9
#define KP     16               // K padded 9 -> 16 for 32x32x16 MFMA
#define JCH    32               // db chunks (grid.y)
#define CHUNK  (NDB / JCH)      // 512 rows per chunk
#define TILES  (CHUNK / 32)     // 16 j-tiles per chunk
// Split-bf16 cosmax error vs numpy fp32 path <= ~6e-6 (lo*lo 3.8e-6 + accum
// 5e-7 + normalize 2e-7 + numpy's own ~1e-6). Band +-2e-5 keeps 3x margin;
// band population ~= 80 patches -> phase2 recheck is cheap.
#define BAND_LO 0.89998f
#define BAND_HI 0.90002f
#define COPY_BLOCKS 144         // NDB*9/4/256 float4-copy blocks

typedef short bf16x8 __attribute__((ext_vector_type(8)));
typedef float f32x16 __attribute__((ext_vector_type(16)));

#define MAX3(a,b,c) fmaxf(fmaxf((a),(b)),(c))

// numpy-order norm of 9 elements: sqrt(pairwise-8 + remainder), no contraction.
__device__ __forceinline__ float np_norm9(const float* v) {
#pragma clang fp contract(off)
    float q0 = v[0] * v[0], q1 = v[1] * v[1], q2 = v[2] * v[2], q3 = v[3] * v[3];
    float q4 = v[4] * v[4], q5 = v[5] * v[5], q6 = v[6] * v[6], q7 = v[7] * v[7];
    float q8 = v[8] * v[8];
    float s = ((q0 + q1) + (q2 + q3)) + ((q4 + q5) + (q6 + q7));
    s = s + q8;
    return sqrtf(s);
}

// fp32 -> bf16 RTNE (no NaN inputs here), and back
__device__ __forceinline__ unsigned short f2bf(float x) {
    unsigned u = __float_as_uint(x);
    return (unsigned short)((u + 0x7fffu + ((u >> 16) & 1u)) >> 16);
}
__device__ __forceinline__ float bf2f(unsigned short h) {
    return __uint_as_float(((unsigned)h) << 16);
}

// Normalize+split a row of 9 into bf16 hi/lo, K-padded to 16, then write the
// two 16B halves of each array to CALLER-CHOSEN int4 slots (lets phase1 place
// them bank-swizzled). Math identical to the proven staging (absmax=0).
__device__ __forceinline__ void stage_row2(const float* __restrict__ src,
                                           int4* dh0, int4* dh1,
                                           int4* dl0, int4* dl1) {
    float v[WS9];
#pragma unroll
    for (int k = 0; k < WS9; k++) v[k] = src[k];
    float inv = 1.0f / np_norm9(v);
    unsigned short h[KP], l[KP];
#pragma unroll
    for (int k = 0; k < KP; k++) {
        float x = (k < WS9) ? v[k] * inv : 0.0f;
        h[k] = f2bf(x);
        l[k] = f2bf(x - bf2f(h[k]));
    }
    int hw[8], lw[8];
#pragma unroll
    for (int k = 0; k < 8; k++) {
        hw[k] = (int)h[2 * k] | ((int)h[2 * k + 1] << 16);
        lw[k] = (int)l[2 * k] | ((int)l[2 * k + 1] << 16);
    }
    *dh0 = make_int4(hw[0], hw[1], hw[2], hw[3]);
    *dh1 = make_int4(hw[4], hw[5], hw[6], hw[7]);
    *dl0 = make_int4(lw[0], lw[1], lw[2], lw[3]);
    *dl1 = make_int4(lw[4], lw[5], lw[6], lw[7]);
}

// K1: fused prep + phase1 (round-0 structure, proven absmax=0 & 95.4us).
// Block = 256 patches (x) x 512-row db chunk (y). Splits in-block into LDS;
// dot = hi*hi + hi*lo + lo*hi via 32x32x16 bf16 MFMA; chunk cos-max plain-
// stored to partial[y][i] (no atomics, no init).
// NEW vs round 0: db LDS tiles are XOR-swizzled. Logical half h of row r
// lives at int4-slot r*2 + (h ^ ((r>>2)&1)). Unswizzled reads had start-bank
// = col*8 mod 32 (4 quads, 8-way conflict on every K-loop ds_read_b128 ->
// SQ_LDS_BANK_CONFLICT ~1M); the XOR spreads 16 consecutive lanes over all 8
// bank-quads (2-way aliasing = free). Bytes only relocated: MFMA inputs
// bit-identical.
__global__ __launch_bounds__(256) void k_phase1(const float* __restrict__ patches,
                                                const float* __restrict__ db,
                                                float* __restrict__ partial,
                                                int* __restrict__ band_count) {
    __shared__ __align__(16) unsigned short s_dnh[CHUNK * KP];
    __shared__ __align__(16) unsigned short s_dnl[CHUNK * KP];
    __shared__ __align__(16) unsigned short s_pnh[256 * KP];
    __shared__ __align__(16) unsigned short s_pnl[256 * KP];

    if (blockIdx.x == 0 && blockIdx.y == 0 && threadIdx.x == 0) *band_count = 0;

    int jbase = blockIdx.y * CHUNK;
    int ibase = blockIdx.x * 256;

    int4* sh4 = (int4*)s_dnh;
    int4* sl4 = (int4*)s_dnl;
#pragma unroll
    for (int rr = 0; rr < CHUNK / 256; rr++) {
        int r = rr * 256 + (int)threadIdx.x;
        int b = (r >> 2) & 1;                     // swizzle bit
        stage_row2(db + (size_t)(jbase + r) * WS9,
                   &sh4[r * 2 + b], &sh4[r * 2 + (1 - b)],
                   &sl4[r * 2 + b], &sl4[r * 2 + (1 - b)]);
    }
    {   // patch staging: unswizzled (read once per thread, off critical path)
        int r = threadIdx.x;
        stage_row2(patches + (size_t)(ibase + r) * WS9,
                   &((int4*)s_pnh)[r * 2], &((int4*)s_pnh)[r * 2 + 1],
                   &((int4*)s_pnl)[r * 2], &((int4*)s_pnl)[r * 2 + 1]);
    }
    __syncthreads();

    int lane = threadIdx.x & 63;
    int wave = threadIdx.x >> 6;
    int col = lane & 31;
    int half = lane >> 5;
    int i0 = ibase + wave * 64;

    const bf16x8* Ph = (const bf16x8*)s_pnh;   // 2 frags per 16-elem row
    const bf16x8* Pl = (const bf16x8*)s_pnl;
    bf16x8 b_hi0 = Ph[(wave * 64 + col) * 2 + half];
    bf16x8 b_lo0 = Pl[(wave * 64 + col) * 2 + half];
    bf16x8 b_hi1 = Ph[(wave * 64 + 32 + col) * 2 + half];
    bf16x8 b_lo1 = Pl[(wave * 64 + 32 + col) * 2 + half];

    const bf16x8* Ah = (const bf16x8*)s_dnh;
    const bf16x8* Al = (const bf16x8*)s_dnl;
    // swizzled half index for db reads: row = t*32+col, (row>>2)&1 == (col>>2)&1
    int halfs = half ^ ((col >> 2) & 1);

    f32x16 zc = {0.f,0.f,0.f,0.f,0.f,0.f,0.f,0.f,0.f,0.f,0.f,0.f,0.f,0.f,0.f,0.f};
    float rm0 = -3.0e38f, rm1 = -3.0e38f;

#pragma unroll 2
    for (int t = 0; t < TILES; ++t) {
        bf16x8 a_h = Ah[(t * 32 + col) * 2 + halfs];
        bf16x8 a_l = Al[(t * 32 + col) * 2 + halfs];
        f32x16 acc0 = __builtin_amdgcn_mfma_f32_32x32x16_bf16(a_h, b_hi0, zc, 0, 0, 0);
        acc0 = __builtin_amdgcn_mfma_f32_32x32x16_bf16(a_h, b_lo0, acc0, 0, 0, 0);
        acc0 = __builtin_amdgcn_mfma_f32_32x32x16_bf16(a_l, b_hi0, acc0, 0, 0, 0);
        f32x16 acc1 = __builtin_amdgcn_mfma_f32_32x32x16_bf16(a_h, b_hi1, zc, 0, 0, 0);
        acc1 = __builtin_amdgcn_mfma_f32_32x32x16_bf16(a_h, b_lo1, acc1, 0, 0, 0);
        acc1 = __builtin_amdgcn_mfma_f32_32x32x16_bf16(a_l, b_hi1, acc1, 0, 0, 0);
        // max3-fusable tree (max is associative: bit-identical to serial chain)
        {
            float u0 = MAX3(acc0[0],  acc0[1],  acc0[2]);
            float u1 = MAX3(acc0[3],  acc0[4],  acc0[5]);
            float u2 = MAX3(acc0[6],  acc0[7],  acc0[8]);
            float u3 = MAX3(acc0[9],  acc0[10], acc0[11]);
            float u4 = MAX3(acc0[12], acc0[13], acc0[14]);
            float u5 = MAX3(u0, u1, acc0[15]);
            float u6 = MAX3(u2, u3, u4);
            rm0 = MAX3(u5, u6, rm0);
        }
        {
            float u0 = MAX3(acc1[0],  acc1[1],  acc1[2]);
            float u1 = MAX3(acc1[3],  acc1[4],  acc1[5]);
            float u2 = MAX3(acc1[6],  acc1[7],  acc1[8]);
            float u3 = MAX3(acc1[9],  acc1[10], acc1[11]);
            float u4 = MAX3(acc1[12], acc1[13], acc1[14]);
            float u5 = MAX3(u0, u1, acc1[15]);
            float u6 = MAX3(u2, u3, u4);
            rm1 = MAX3(u5, u6, rm1);
        }
    }
    rm0 = fmaxf(rm0, __shfl_xor(rm0, 32, 64));
    rm1 = fmaxf(rm1, __shfl_xor(rm1, 32, 64));
    int ti = half ? (i0 + 32 + col) : (i0 + col);
    partial[(size_t)blockIdx.y * NPATCH + ti] = half ? rm1 : rm0;
}

// K2: blocks [0,144) copy db rows to out (float4); blocks [144,208) classify:
// max over 32 chunk-partials, definite rows written, band -> global list.
__global__ __launch_bounds__(256) void k_finish(const float* __restrict__ patches,
                                                const float* __restrict__ db,
                                                const float* __restrict__ partial,
                                                float* __restrict__ out,
                                                int* __restrict__ band_list,
                                                int* __restrict__ band_count) {
    int b = blockIdx.x;
    if (b < COPY_BLOCKS) {
        int e = b * 256 + threadIdx.x;          // 36864 float4 = 147456 floats
        ((float4*)out)[e] = ((const float4*)db)[e];
        return;
    }
    int i = (b - COPY_BLOCKS) * 256 + threadIdx.x;
    float cosmax = partial[i];
#pragma unroll
    for (int c = 1; c < JCH; c++)
        cosmax = fmaxf(cosmax, partial[(size_t)c * NPATCH + i]);
    if (cosmax >= BAND_LO && cosmax < BAND_HI) {
        int idx = atomicAdd(band_count, 1);
        band_list[idx] = i;
        return;  // row written by phase 2
    }
    int hit = (cosmax >= BAND_HI) ? 1 : 0;
#pragma unroll
    for (int k = 0; k < WS9; k++)
        out[(size_t)(NDB + i) * WS9 + k] = hit ? 0.0f : patches[(size_t)i * WS9 + k];
}

// K3: exact numpy-mirror recheck for band patches (proven absmax=0).
// 256 blocks grid-stride over ~80 entries -> <=1 entry per block typically.
__global__ __launch_bounds__(256) void k_phase2(const float* __restrict__ patches,
                                                const float* __restrict__ db,
                                                const int* __restrict__ band_list,
                                                const int* __restrict__ band_count,
                                                float* __restrict__ out) {
    __shared__ float sp[WS9];
    __shared__ float snp;
    __shared__ int shit;
    int nb = *band_count;
    for (int idx = blockIdx.x; idx < nb; idx += gridDim.x) {
        int i = band_list[idx];
        if (threadIdx.x == 0) {
            float p[WS9];
            for (int k = 0; k < WS9; k++) { p[k] = patches[(size_t)i * WS9 + k]; sp[k] = p[k]; }
            snp = np_norm9(p);
            shit = 0;
        }
        __syncthreads();
        float p[WS9];
#pragma unroll
        for (int k = 0; k < WS9; k++) p[k] = sp[k];
        float npn = snp;
        int hit = 0;
        for (int j = (int)threadIdx.x; j < NDB; j += 256) {
            float d[WS9];
#pragma unroll
            for (int k = 0; k < WS9; k++) d[k] = db[(size_t)j * WS9 + k];
            float dot = 0.0f;
#pragma unroll
            for (int k = 0; k < WS9; k++) dot = fmaf(p[k], d[k], dot);
            float nd = np_norm9(d);
            float cs = dot / (npn * nd);          // IEEE fp32 divide
            if (!((double)cs < 0.9)) hit = 1;     // numpy promotes to f64
        }
        if (hit) atomicOr(&shit, 1);
        __syncthreads();
        int m = shit;
        if (threadIdx.x < WS9)
            out[(size_t)(NDB + i) * WS9 + threadIdx.x] = m ? 0.0f : sp[threadIdx.x];
        __syncthreads();
    }
}

extern "C" void kernel_launch(void* const* d_in, const int* in_sizes, int n_in,
                              void* d_out, int out_size, void* d_ws, size_t ws_size,
                              hipStream_t stream) {
    const float* patches = (const float*)d_in[0];  // [16384][9]
    const float* db      = (const float*)d_in[1];  // [16384][9]
    float* out = (float*)d_out;                    // [32768][9]

    // ws layout: partial (JCH*NPATCH f32 = 2 MB) | band_list (64 KB) | band_count
    char* wsb = (char*)d_ws;
    float* partial    = (float*)wsb;
    int*   band_list  = (int*)(wsb + (size_t)JCH * NPATCH * 4);
    int*   band_count = (int*)(wsb + (size_t)JCH * NPATCH * 4 + (size_t)NPATCH * 4);

    k_phase1<<<dim3(NPATCH / 256, JCH), dim3(256), 0, stream>>>(patches, db,
                                                                partial, band_count);
    k_finish<<<dim3(COPY_BLOCKS + NPATCH / 256), dim3(256), 0, stream>>>(
        patches, db, partial, out, band_list, band_count);
    k_phase2<<<dim3(256), dim3(256), 0, stream>>>(patches, db, band_list, band_count, out);
}